// Round 7
// baseline (89.696 us; speedup 1.0000x reference)
//
#include <hip/hip_runtime.h>
#include <hip/hip_bf16.h>
#include <math.h>

#define S_LEN 2048
#define EDIM  1024
#define NHEAD 8
#define DHEAD 128
#define QT    32
#define NT    64            // S_LEN/QT
#define SCL   0.08838834764831845f   // 1/sqrt(128)

typedef __bf16 bf16x8 __attribute__((ext_vector_type(8)));
typedef __bf16 bf16x2 __attribute__((ext_vector_type(2)));
typedef float  f32x16 __attribute__((ext_vector_type(16)));
typedef unsigned int u32x4 __attribute__((ext_vector_type(4)));

__device__ __forceinline__ unsigned pk2(float a, float b) {
  bf16x2 t; t[0] = (__bf16)a; t[1] = (__bf16)b;
  return __builtin_bit_cast(unsigned, t);
}
__device__ __forceinline__ unsigned short bfb(float x) {
  return __builtin_bit_cast(unsigned short, (__bf16)x);
}
__device__ __forceinline__ void lane32_swap(unsigned &x, unsigned &y) {
  asm volatile("v_permlane32_swap_b32 %0, %1" : "+v"(x), "+v"(y));
}
// compile-time float4 component select
#define F4C(v, c) ((c)==0 ? (v).x : (c)==1 ? (v).y : (c)==2 ? (v).z : (v).w)

// ---------------- Kernel 1: gates + fragment-order bf16 pack ----------------
// Block = 8 s-rows (one V e-octet). Packs Qp/Kp/Vp so main-kernel fragment
// loads are single coalesced 1KB dwordx4 per (wave, ks).
//   Qp/Kp entry(h,tile,ks,l)      : row tile*32+(l&31), elems h*128+(l>>5)*8+ks*16+e
//   Vp entry(h,tile,ksv,db,l)     : col h*128+db*32+(l&31), rows tile*32+(l>>5)*8+ksv*16+e
__global__ __launch_bounds__(256) void gates_pack_kernel(
    const float* __restrict__ q, const float* __restrict__ k, const float* __restrict__ v,
    const float* __restrict__ iw, const float* __restrict__ ib,
    const float* __restrict__ fw, const float* __restrict__ fb,
    float* __restrict__ ig, float* __restrict__ fg,
    unsigned short* __restrict__ Qp, unsigned short* __restrict__ Kp,
    unsigned short* __restrict__ Vp)
{
  __shared__ float gl[8][3072];
  const int s0 = blockIdx.x * 8;
  const int t = threadIdx.x;
  const int w = t >> 6, lane = t & 63;
  // phase A: stage 8 rows of concat(q,k,v)
  #pragma unroll
  for (int rr = 0; rr < 8; ++rr) {
    const float4* qs = (const float4*)(q + (size_t)(s0+rr)*EDIM);
    const float4* ks = (const float4*)(k + (size_t)(s0+rr)*EDIM);
    const float4* vs = (const float4*)(v + (size_t)(s0+rr)*EDIM);
    float4* dst = (float4*)&gl[rr][0];
    dst[t]       = qs[t];
    dst[t + 256] = ks[t];
    dst[t + 512] = vs[t];
  }
  __syncthreads();
  // phase B: dots. wave w -> outputs c in {w, w+4, w+8, w+12}, 8 rows each.
  float sum[4][8];
  #pragma unroll
  for (int ci = 0; ci < 4; ++ci)
    #pragma unroll
    for (int rr = 0; rr < 8; ++rr) sum[ci][rr] = 0.f;
  for (int ch = 0; ch < 12; ++ch) {
    float4 wv[4];
    #pragma unroll
    for (int ci = 0; ci < 4; ++ci) {
      const int c = w + 4*ci;
      const float* wr = (c >= 8 ? fw : iw) + (size_t)(c & 7)*3*EDIM;
      wv[ci] = ((const float4*)wr)[ch*64 + lane];
    }
    #pragma unroll
    for (int rr = 0; rr < 8; ++rr) {
      const float4 g = ((const float4*)&gl[rr][0])[ch*64 + lane];
      #pragma unroll
      for (int ci = 0; ci < 4; ++ci)
        sum[ci][rr] += g.x*wv[ci].x + g.y*wv[ci].y + g.z*wv[ci].z + g.w*wv[ci].w;
    }
  }
  #pragma unroll
  for (int ci = 0; ci < 4; ++ci)
    #pragma unroll
    for (int rr = 0; rr < 8; ++rr) {
      float s = sum[ci][rr];
      #pragma unroll
      for (int off = 32; off; off >>= 1) s += __shfl_xor(s, off);
      if (lane == 0) {
        const int c = w + 4*ci;
        const int hh = c & 7;
        if (c >= 8) fg[hh*S_LEN + s0 + rr] = s + fb[hh];
        else        ig[hh*S_LEN + s0 + rr] = s + ib[hh];
      }
    }
  // phase C: pack Q (xSCL) and K. thread t owns elems 4t..4t+3 of each row.
  {
    const int hh = t >> 5;
    const int ks = (t >> 2) & 7;
    const int hi = (t >> 1) & 1;
    const int half = (t & 1);           // 8B half within 16B entry
    const int jt = s0 >> 5;
    #pragma unroll
    for (int rr = 0; rr < 8; ++rr) {
      const int l31 = (s0 & 31) + rr;
      const size_t idx16 = ((size_t)(hh*64 + jt)*8 + ks)*64 + hi*32 + l31;
      const float4 qv = ((const float4*)&gl[rr][0])[t];
      const float4 kv = ((const float4*)&gl[rr][0])[t + 256];
      ushort4 qo, ko;
      qo.x = bfb(qv.x*SCL); qo.y = bfb(qv.y*SCL); qo.z = bfb(qv.z*SCL); qo.w = bfb(qv.w*SCL);
      ko.x = bfb(kv.x); ko.y = bfb(kv.y); ko.z = bfb(kv.z); ko.w = bfb(kv.w);
      *(ushort4*)(Qp + idx16*8 + half*4) = qo;
      *(ushort4*)(Kp + idx16*8 + half*4) = ko;
    }
  }
  // phase D: pack V (transposed). Block covers one e-octet (8 rows).
  {
    const int hh  = t >> 5;
    const int c31 = t & 31;
    const int jt  = s0 >> 5;
    const int o   = (s0 & 31) >> 3;     // octet index within tile
    const int hiv = o & 1, ksv = o >> 1;
    #pragma unroll
    for (int db = 0; db < 4; ++db) {
      const int col = hh*128 + db*32 + c31;
      bf16x8 e;
      #pragma unroll
      for (int rr = 0; rr < 8; ++rr) e[rr] = (__bf16)gl[rr][2048 + col];
      const size_t idx16 = (((size_t)(hh*64 + jt)*2 + ksv)*4 + db)*64 + hiv*32 + c31;
      *(bf16x8*)(Vp + idx16*8) = e;
    }
  }
}

// ---------------- Kernel 2: per-head scans (shfl-based, 2 barriers) ---------
__global__ __launch_bounds__(256) void scan_kernel(
    const float* __restrict__ ig, const float* __restrict__ fg,
    float* __restrict__ cs, float* __restrict__ a, float* __restrict__ M)
{
  __shared__ float wsum[4];
  __shared__ float wmax[4];
  const int h = blockIdx.x, t = threadIdx.x;
  const int w = t >> 6, lane = t & 63;
  const int base = t*8;
  const float* fgh = fg + h*S_LEN;
  const float* igh = ig + h*S_LEN;
  float lv[8];
  float loc = 0.f;
  #pragma unroll
  for (int i2 = 0; i2 < 8; ++i2) {
    float x = fgh[base + i2];
    float ls = fminf(x, 0.f) - log1pf(expf(-fabsf(x)));
    lv[i2] = ls; loc += ls;
  }
  float sc = loc;
  #pragma unroll
  for (int off = 1; off < 64; off <<= 1) {
    float u = __shfl_up(sc, off);
    sc += (lane >= off) ? u : 0.f;
  }
  if (lane == 63) wsum[w] = sc;
  __syncthreads();
  float prefix = 0.f;
  #pragma unroll
  for (int ww = 0; ww < 4; ++ww) if (ww < w) prefix += wsum[ww];
  float c = prefix + sc - loc;  // exclusive prefix for this thread
  float av[8]; float lmax = -INFINITY;
  #pragma unroll
  for (int i2 = 0; i2 < 8; ++i2) {
    c += lv[i2];
    cs[h*S_LEN + base + i2] = c;
    float ai = igh[base + i2] - c;
    av[i2] = ai;
    a[h*S_LEN + base + i2] = ai;
    lmax = fmaxf(lmax, ai);
  }
  float sm = lmax;
  #pragma unroll
  for (int off = 1; off < 64; off <<= 1) {
    float u = __shfl_up(sm, off);
    sm = (lane >= off) ? fmaxf(sm, u) : sm;
  }
  if (lane == 63) wmax[w] = sm;
  __syncthreads();
  float pmax = -INFINITY;
  #pragma unroll
  for (int ww = 0; ww < 4; ++ww) if (ww < w) pmax = fmaxf(pmax, wmax[ww]);
  float ex = __shfl_up(sm, 1);
  float m = fmaxf(pmax, (lane == 0) ? -INFINITY : ex);
  #pragma unroll
  for (int i2 = 0; i2 < 8; ++i2) {
    m = fmaxf(m, av[i2]);
    M[h*S_LEN + base + i2] = m;
  }
}

// ---------------- Kernel 3: MFMA main, fully prefetched bodies --------------
// Balanced pairing: co-resident blocks carry tiles (63-m, m) -> 65 j-tiles/CU.
// K, V, AND a[] are all double-buffered one body ahead (grid-limited occupancy
// means VGPRs up to 256 are free -> spend them on pipeline depth). Bodies
// contain zero loads; counted-vmcnt waits get a full body (~600 cyc) of slack.
__global__ __launch_bounds__(256, 2) void mlstm_main(
    const unsigned short* __restrict__ Qp, const unsigned short* __restrict__ Kp,
    const unsigned short* __restrict__ Vp,
    const float* __restrict__ cs, const float* __restrict__ a, const float* __restrict__ M,
    const float* __restrict__ out_w, float* __restrict__ out)
{
  __shared__ float red[2][QT][DHEAD];
  __shared__ float rs_red[2][QT];

  const int bb  = blockIdx.x;
  const int h   = bb & 7;          // head -> XCD locality
  const int l   = bb >> 3;         // 0..63
  const int it  = (l < 32) ? (63 - l) : (l - 32);   // balanced big/small pairing
  const int t   = threadIdx.x;
  const int w   = t >> 6;
  const int lane = t & 63;
  const int q32 = lane & 31;
  const int hi  = lane >> 5;

  const bf16x8* QP8 = (const bf16x8*)Qp;
  const bf16x8* KP8 = (const bf16x8*)Kp;
  const bf16x8* VP8 = (const bf16x8*)Vp;
  const float* ah = a + h*S_LEN;

  const int i0 = it*QT;
  const int iq = i0 + q32;
  const float Mi = M[h*S_LEN + iq];

  bf16x8 qf[8];
  {
    const size_t qb = ((size_t)(h*64 + it)*8)*64 + lane;
    #pragma unroll
    for (int ks = 0; ks < 8; ++ks) qf[ks] = QP8[qb + ks*64];
  }
  f32x16 acc[4];
  #pragma unroll
  for (int db = 0; db < 4; ++db)
    #pragma unroll
    for (int r = 0; r < 16; ++r) acc[db][r] = 0.f;
  float rs = 0.f;

  bf16x8 kA[8], kB[8];
  bf16x8 vA[8], vB[8];     // flat index x = ksv*4 + db
  float4 aA[4], aB[4];

  #define LOADALL(KB_, VB_, AB_, JT) do {                               \
      const size_t base_ = ((size_t)(h*64 + (JT))*8)*64 + lane;         \
      _Pragma("unroll")                                                 \
      for (int ks_ = 0; ks_ < 8; ++ks_) KB_[ks_] = KP8[base_ + ks_*64]; \
      _Pragma("unroll")                                                 \
      for (int x_ = 0; x_ < 8; ++x_) VB_[x_] = VP8[base_ + x_*64];      \
      _Pragma("unroll")                                                 \
      for (int g_ = 0; g_ < 4; ++g_)                                    \
        AB_[g_] = *(const float4*)&ah[(JT)*QT + 8*g_ + 4*hi];           \
    } while (0)

  #define BODY(KF, VF, AF, JT) do {                                     \
      f32x16 st0, st1;                                                  \
      _Pragma("unroll")                                                 \
      for (int r_ = 0; r_ < 16; ++r_) { st0[r_] = 0.f; st1[r_] = 0.f; } \
      _Pragma("unroll")                                                 \
      for (int ks_ = 0; ks_ < 4; ++ks_) {                               \
        st0 = __builtin_amdgcn_mfma_f32_32x32x16_bf16(KF[2*ks_],   qf[2*ks_],   st0, 0, 0, 0); \
        st1 = __builtin_amdgcn_mfma_f32_32x32x16_bf16(KF[2*ks_+1], qf[2*ks_+1], st1, 0, 0, 0); \
      }                                                                 \
      const bool diag_ = ((JT) == it);                                  \
      float pw[16]; float rsl_ = 0.f;                                   \
      _Pragma("unroll")                                                 \
      for (int r_ = 0; r_ < 16; ++r_) {                                 \
        const int jl_ = (r_&3) + 8*(r_>>2) + 4*hi;                      \
        const float av_ = F4C(AF[r_>>2], r_&3);                         \
        float cv_ = (st0[r_] + st1[r_]) * __expf(av_ - Mi);             \
        if (diag_ && jl_ > q32) cv_ = 0.f;                              \
        pw[r_] = cv_; rsl_ += cv_;                                      \
      }                                                                 \
      rs += rsl_;                                                       \
      unsigned w00 = pk2(pw[0],pw[1]),   w02 = pk2(pw[4],pw[5]);        \
      unsigned w01 = pk2(pw[2],pw[3]),   w03 = pk2(pw[6],pw[7]);        \
      unsigned w10 = pk2(pw[8],pw[9]),   w12 = pk2(pw[12],pw[13]);      \
      unsigned w11 = pk2(pw[10],pw[11]), w13 = pk2(pw[14],pw[15]);      \
      lane32_swap(w00, w02); lane32_swap(w01, w03);                     \
      lane32_swap(w10, w12); lane32_swap(w11, w13);                     \
      u32x4 a0v; a0v[0]=w00; a0v[1]=w01; a0v[2]=w02; a0v[3]=w03;        \
      u32x4 a1v; a1v[0]=w10; a1v[1]=w11; a1v[2]=w12; a1v[3]=w13;        \
      const bf16x8 pa0 = __builtin_bit_cast(bf16x8, a0v);               \
      const bf16x8 pa1 = __builtin_bit_cast(bf16x8, a1v);               \
      _Pragma("unroll")                                                 \
      for (int db_ = 0; db_ < 4; ++db_) {                               \
        acc[db_] = __builtin_amdgcn_mfma_f32_32x32x16_bf16(pa0, VF[db_],   acc[db_], 0, 0, 0); \
        acc[db_] = __builtin_amdgcn_mfma_f32_32x32x16_bf16(pa1, VF[4+db_], acc[db_], 0, 0, 0); \
      }                                                                 \
    } while (0)

  int jt = w;
  if (jt <= it) LOADALL(kA, vA, aA, jt);
  while (jt <= it) {
    int nx = jt + 4;
    if (nx <= it) LOADALL(kB, vB, aB, nx);
    BODY(kA, vA, aA, jt);
    jt = nx;
    if (jt > it) break;
    nx = jt + 4;
    if (nx <= it) LOADALL(kA, vA, aA, nx);
    BODY(kB, vB, aB, jt);
    jt = nx;
  }
  #undef LOADALL
  #undef BODY

  rs += __shfl_xor(rs, 32);

  // ---- 2-step cross-wave tree reduction in LDS ----
  if (w >= 2) {
    #pragma unroll
    for (int db = 0; db < 4; ++db)
      #pragma unroll
      for (int r = 0; r < 16; ++r) {
        const int row = (r&3) + 8*(r>>2) + 4*hi;
        red[w-2][row][db*32 + q32] = acc[db][r];
      }
    if (lane < 32) rs_red[w-2][q32] = rs;
  }
  __syncthreads();
  if (w < 2) {
    #pragma unroll
    for (int db = 0; db < 4; ++db)
      #pragma unroll
      for (int r = 0; r < 16; ++r) {
        const int row = (r&3) + 8*(r>>2) + 4*hi;
        acc[db][r] += red[w][row][db*32 + q32];
      }
    rs += rs_red[w][q32];
    #pragma unroll
    for (int db = 0; db < 4; ++db)
      #pragma unroll
      for (int r = 0; r < 16; ++r) {
        const int row = (r&3) + 8*(r>>2) + 4*hi;
        red[w][row][db*32 + q32] = acc[db][r];
      }
    if (lane < 32) rs_red[w][q32] = rs;
  }
  __syncthreads();

  // ---- epilogue: normalizer + per-head LayerNorm ----
  {
    const int r2 = t >> 3;
    const int l8 = t & 7;
    const int i  = i0 + r2;
    const float rst = rs_red[0][r2] + rs_red[1][r2];
    const float csi = cs[h*S_LEN + i];
    const float Mi2 = M[h*S_LEN + i];
    const float norm = fmaxf(fabsf(rst), __expf(-(csi + Mi2))) + 1e-6f;
    const float inv = 1.0f / norm;
    float hv[16]; float s1 = 0.f, s2 = 0.f;
    #pragma unroll
    for (int u = 0; u < 4; ++u) {
      const int d = l8*4 + u*32;
      #pragma unroll
      for (int c2 = 0; c2 < 4; ++c2) {
        float x = (red[0][r2][d+c2] + red[1][r2][d+c2]) * inv;
        hv[u*4+c2] = x; s1 += x; s2 += x*x;
      }
    }
    s1 += __shfl_xor(s1,1); s1 += __shfl_xor(s1,2); s1 += __shfl_xor(s1,4);
    s2 += __shfl_xor(s2,1); s2 += __shfl_xor(s2,2); s2 += __shfl_xor(s2,4);
    const float mean = s1*(1.f/DHEAD);
    const float var  = s2*(1.f/DHEAD) - mean*mean;
    const float rstd = rsqrtf(var + 1e-5f);
    float* op = out + (size_t)i*EDIM + h*DHEAD;
    const float* ow = out_w + h*DHEAD;
    #pragma unroll
    for (int u = 0; u < 4; ++u) {
      const int d = l8*4 + u*32;
      float4 o;
      o.x = (hv[u*4+0]-mean)*rstd*ow[d+0];
      o.y = (hv[u*4+1]-mean)*rstd*ow[d+1];
      o.z = (hv[u*4+2]-mean)*rstd*ow[d+2];
      o.w = (hv[u*4+3]-mean)*rstd*ow[d+3];
      *((float4*)(op + d)) = o;
    }
  }
}

extern "C" void kernel_launch(void* const* d_in, const int* in_sizes, int n_in,
                              void* d_out, int out_size, void* d_ws, size_t ws_size,
                              hipStream_t stream) {
  const float* q  = (const float*)d_in[0];
  const float* k  = (const float*)d_in[1];
  const float* v  = (const float*)d_in[2];
  const float* iw = (const float*)d_in[3];
  const float* ib = (const float*)d_in[4];
  const float* fw = (const float*)d_in[5];
  const float* fb = (const float*)d_in[6];
  const float* ow = (const float*)d_in[7];
  float* out = (float*)d_out;
  float* ws = (float*)d_ws;
  float* ig = ws;
  float* fg = ws + 1*NHEAD*S_LEN;
  float* cs = ws + 2*NHEAD*S_LEN;
  float* aa = ws + 3*NHEAD*S_LEN;
  float* Mm = ws + 4*NHEAD*S_LEN;
  unsigned short* Qp = (unsigned short*)(ws + 5*NHEAD*S_LEN);
  unsigned short* Kp = Qp + (size_t)S_LEN*EDIM;
  unsigned short* Vp = Kp + (size_t)S_LEN*EDIM;

  hipLaunchKernelGGL(gates_pack_kernel, dim3(S_LEN/8), dim3(256), 0, stream,
                     q, k, v, iw, ib, fw, fb, ig, fg, Qp, Kp, Vp);
  hipLaunchKernelGGL(scan_kernel, dim3(NHEAD), dim3(256), 0, stream,
                     ig, fg, cs, aa, Mm);
  hipLaunchKernelGGL(mlstm_main, dim3(NHEAD*NT), dim3(256), 0, stream,
                     Qp, Kp, Vp, cs, aa, Mm, ow, out);
}

// Round 8
// 52.923 us; speedup vs baseline: 1.6948x; 1.6948x over previous
//
#include <hip/hip_runtime.h>
#include <hip/hip_bf16.h>
#include <math.h>

#define S_LEN 2048
#define EDIM  1024
#define NHEAD 8
#define DHEAD 128
#define QT    32
#define NT    64            // S_LEN/QT
#define SCL   0.08838834764831845f   // 1/sqrt(128)

typedef __bf16 bf16x8 __attribute__((ext_vector_type(8)));
typedef __bf16 bf16x2 __attribute__((ext_vector_type(2)));
typedef float  f32x16 __attribute__((ext_vector_type(16)));
typedef unsigned int u32x4 __attribute__((ext_vector_type(4)));

__device__ __forceinline__ unsigned pk2(float a, float b) {
  bf16x2 t; t[0] = (__bf16)a; t[1] = (__bf16)b;
  return __builtin_bit_cast(unsigned, t);
}
__device__ __forceinline__ unsigned short bfb(float x) {
  return __builtin_bit_cast(unsigned short, (__bf16)x);
}
__device__ __forceinline__ void lane32_swap(unsigned &x, unsigned &y) {
  asm volatile("v_permlane32_swap_b32 %0, %1" : "+v"(x), "+v"(y));
}
// compile-time float4 component select
#define F4C(v, c) ((c)==0 ? (v).x : (c)==1 ? (v).y : (c)==2 ? (v).z : (v).w)

// ---------------- Kernel 1: gates + fragment-order bf16 pack ----------------
// (unchanged from R6 — proven)
__global__ __launch_bounds__(256) void gates_pack_kernel(
    const float* __restrict__ q, const float* __restrict__ k, const float* __restrict__ v,
    const float* __restrict__ iw, const float* __restrict__ ib,
    const float* __restrict__ fw, const float* __restrict__ fb,
    float* __restrict__ ig, float* __restrict__ fg,
    unsigned short* __restrict__ Qp, unsigned short* __restrict__ Kp,
    unsigned short* __restrict__ Vp)
{
  __shared__ float gl[8][3072];
  const int s0 = blockIdx.x * 8;
  const int t = threadIdx.x;
  const int w = t >> 6, lane = t & 63;
  #pragma unroll
  for (int rr = 0; rr < 8; ++rr) {
    const float4* qs = (const float4*)(q + (size_t)(s0+rr)*EDIM);
    const float4* ks = (const float4*)(k + (size_t)(s0+rr)*EDIM);
    const float4* vs = (const float4*)(v + (size_t)(s0+rr)*EDIM);
    float4* dst = (float4*)&gl[rr][0];
    dst[t]       = qs[t];
    dst[t + 256] = ks[t];
    dst[t + 512] = vs[t];
  }
  __syncthreads();
  float sum[4][8];
  #pragma unroll
  for (int ci = 0; ci < 4; ++ci)
    #pragma unroll
    for (int rr = 0; rr < 8; ++rr) sum[ci][rr] = 0.f;
  for (int ch = 0; ch < 12; ++ch) {
    float4 wv[4];
    #pragma unroll
    for (int ci = 0; ci < 4; ++ci) {
      const int c = w + 4*ci;
      const float* wr = (c >= 8 ? fw : iw) + (size_t)(c & 7)*3*EDIM;
      wv[ci] = ((const float4*)wr)[ch*64 + lane];
    }
    #pragma unroll
    for (int rr = 0; rr < 8; ++rr) {
      const float4 g = ((const float4*)&gl[rr][0])[ch*64 + lane];
      #pragma unroll
      for (int ci = 0; ci < 4; ++ci)
        sum[ci][rr] += g.x*wv[ci].x + g.y*wv[ci].y + g.z*wv[ci].z + g.w*wv[ci].w;
    }
  }
  #pragma unroll
  for (int ci = 0; ci < 4; ++ci)
    #pragma unroll
    for (int rr = 0; rr < 8; ++rr) {
      float s = sum[ci][rr];
      #pragma unroll
      for (int off = 32; off; off >>= 1) s += __shfl_xor(s, off);
      if (lane == 0) {
        const int c = w + 4*ci;
        const int hh = c & 7;
        if (c >= 8) fg[hh*S_LEN + s0 + rr] = s + fb[hh];
        else        ig[hh*S_LEN + s0 + rr] = s + ib[hh];
      }
    }
  {
    const int hh = t >> 5;
    const int ks = (t >> 2) & 7;
    const int hi = (t >> 1) & 1;
    const int half = (t & 1);
    const int jt = s0 >> 5;
    #pragma unroll
    for (int rr = 0; rr < 8; ++rr) {
      const int l31 = (s0 & 31) + rr;
      const size_t idx16 = ((size_t)(hh*64 + jt)*8 + ks)*64 + hi*32 + l31;
      const float4 qv = ((const float4*)&gl[rr][0])[t];
      const float4 kv = ((const float4*)&gl[rr][0])[t + 256];
      ushort4 qo, ko;
      qo.x = bfb(qv.x*SCL); qo.y = bfb(qv.y*SCL); qo.z = bfb(qv.z*SCL); qo.w = bfb(qv.w*SCL);
      ko.x = bfb(kv.x); ko.y = bfb(kv.y); ko.z = bfb(kv.z); ko.w = bfb(kv.w);
      *(ushort4*)(Qp + idx16*8 + half*4) = qo;
      *(ushort4*)(Kp + idx16*8 + half*4) = ko;
    }
  }
  {
    const int hh  = t >> 5;
    const int c31 = t & 31;
    const int jt  = s0 >> 5;
    const int o   = (s0 & 31) >> 3;
    const int hiv = o & 1, ksv = o >> 1;
    #pragma unroll
    for (int db = 0; db < 4; ++db) {
      const int col = hh*128 + db*32 + c31;
      bf16x8 e;
      #pragma unroll
      for (int rr = 0; rr < 8; ++rr) e[rr] = (__bf16)gl[rr][2048 + col];
      const size_t idx16 = (((size_t)(hh*64 + jt)*2 + ksv)*4 + db)*64 + hiv*32 + c31;
      *(bf16x8*)(Vp + idx16*8) = e;
    }
  }
}

// ---------------- Kernel 2: per-head scans (unchanged from R6) --------------
__global__ __launch_bounds__(256) void scan_kernel(
    const float* __restrict__ ig, const float* __restrict__ fg,
    float* __restrict__ cs, float* __restrict__ a, float* __restrict__ M)
{
  __shared__ float wsum[4];
  __shared__ float wmax[4];
  const int h = blockIdx.x, t = threadIdx.x;
  const int w = t >> 6, lane = t & 63;
  const int base = t*8;
  const float* fgh = fg + h*S_LEN;
  const float* igh = ig + h*S_LEN;
  float lv[8];
  float loc = 0.f;
  #pragma unroll
  for (int i2 = 0; i2 < 8; ++i2) {
    float x = fgh[base + i2];
    float ls = fminf(x, 0.f) - log1pf(expf(-fabsf(x)));
    lv[i2] = ls; loc += ls;
  }
  float sc = loc;
  #pragma unroll
  for (int off = 1; off < 64; off <<= 1) {
    float u = __shfl_up(sc, off);
    sc += (lane >= off) ? u : 0.f;
  }
  if (lane == 63) wsum[w] = sc;
  __syncthreads();
  float prefix = 0.f;
  #pragma unroll
  for (int ww = 0; ww < 4; ++ww) if (ww < w) prefix += wsum[ww];
  float c = prefix + sc - loc;
  float av[8]; float lmax = -INFINITY;
  #pragma unroll
  for (int i2 = 0; i2 < 8; ++i2) {
    c += lv[i2];
    cs[h*S_LEN + base + i2] = c;
    float ai = igh[base + i2] - c;
    av[i2] = ai;
    a[h*S_LEN + base + i2] = ai;
    lmax = fmaxf(lmax, ai);
  }
  float sm = lmax;
  #pragma unroll
  for (int off = 1; off < 64; off <<= 1) {
    float u = __shfl_up(sm, off);
    sm = (lane >= off) ? fmaxf(sm, u) : sm;
  }
  if (lane == 63) wmax[w] = sm;
  __syncthreads();
  float pmax = -INFINITY;
  #pragma unroll
  for (int ww = 0; ww < 4; ++ww) if (ww < w) pmax = fmaxf(pmax, wmax[ww]);
  float ex = __shfl_up(sm, 1);
  float m = fmaxf(pmax, (lane == 0) ? -INFINITY : ex);
  #pragma unroll
  for (int i2 = 0; i2 < 8; ++i2) {
    m = fmaxf(m, av[i2]);
    M[h*S_LEN + base + i2] = m;
  }
}

// ---------------- Kernel 3: MFMA main; V via LDS global_load_lds ------------
// K + a[] register-double-buffered (distance 1). V double-buffered in per-wave
// private LDS via global_load_lds (no VGPR cost, deep vmcnt queue). One
// explicit vmcnt(0) per body before the PV ds_reads; stage for body n+1 is
// issued AFTER those reads so it is never drained same-body.
__global__ __launch_bounds__(256, 2) void mlstm_main(
    const unsigned short* __restrict__ Qp, const unsigned short* __restrict__ Kp,
    const unsigned short* __restrict__ Vp,
    const float* __restrict__ cs, const float* __restrict__ a, const float* __restrict__ M,
    const float* __restrict__ out_w, float* __restrict__ out)
{
  // V staging (4 waves x 2 bufs x 8KB = 64KB), unioned with the post-loop
  // reduction buffer (32KB) -- a __syncthreads() separates the lifetimes.
  __shared__ __align__(16) unsigned char sm_u[4*2*8192];
  __shared__ float rs_red[2][QT];
  float (*red)[QT][DHEAD] = (float (*)[QT][DHEAD])sm_u;

  const int bb  = blockIdx.x;
  const int h   = bb & 7;          // head -> XCD locality
  const int l   = bb >> 3;         // 0..63
  const int it  = (l < 32) ? (63 - l) : (l - 32);   // balanced big/small pairing
  const int t   = threadIdx.x;
  const int w   = t >> 6;
  const int lane = t & 63;
  const int q32 = lane & 31;
  const int hi  = lane >> 5;

  const bf16x8* QP8 = (const bf16x8*)Qp;
  const bf16x8* KP8 = (const bf16x8*)Kp;
  const bf16x8* VP8 = (const bf16x8*)Vp;
  const float* ah = a + h*S_LEN;

  const int i0 = it*QT;
  const int iq = i0 + q32;
  const float Mi = M[h*S_LEN + iq];

  bf16x8 qf[8];
  {
    const size_t qb = ((size_t)(h*64 + it)*8)*64 + lane;
    #pragma unroll
    for (int ks = 0; ks < 8; ++ks) qf[ks] = QP8[qb + ks*64];
  }
  f32x16 acc[4];
  #pragma unroll
  for (int db = 0; db < 4; ++db)
    #pragma unroll
    for (int r = 0; r < 16; ++r) acc[db][r] = 0.f;
  float rs = 0.f;

  bf16x8 kA[8], kB[8];
  float4 aA[4], aB[4];
  unsigned char* vbase = sm_u + w*16384;   // this wave's 2 V buffers

  #define LOADKA(KB_, AB_, JT) do {                                     \
      const size_t kb_ = ((size_t)(h*64 + (JT))*8)*64 + lane;           \
      _Pragma("unroll")                                                 \
      for (int ks_ = 0; ks_ < 8; ++ks_) KB_[ks_] = KP8[kb_ + ks_*64];   \
      _Pragma("unroll")                                                 \
      for (int g_ = 0; g_ < 4; ++g_)                                    \
        AB_[g_] = *(const float4*)&ah[(JT)*QT + 8*g_ + 4*hi];           \
    } while (0)

  // async V stage: per-lane global src, wave-uniform LDS dst (+lane*16 by HW)
  #define STAGEV(BUFI, JT) do {                                         \
      const size_t vsrc_ = ((size_t)(h*64 + (JT))*8)*64 + lane;         \
      unsigned char* vd_ = vbase + (BUFI)*8192;                         \
      _Pragma("unroll")                                                 \
      for (int x_ = 0; x_ < 8; ++x_)                                    \
        __builtin_amdgcn_global_load_lds(                               \
          (const __attribute__((address_space(1))) unsigned int*)(const void*)(VP8 + vsrc_ + (size_t)x_*64), \
          (__attribute__((address_space(3))) unsigned int*)(void*)(vd_ + x_*1024), \
          16, 0, 0);                                                    \
    } while (0)

  #define BODY(KF, AF, BUFI, JT, NX, NBUF) do {                         \
      f32x16 st0, st1;                                                  \
      _Pragma("unroll")                                                 \
      for (int r_ = 0; r_ < 16; ++r_) { st0[r_] = 0.f; st1[r_] = 0.f; } \
      _Pragma("unroll")                                                 \
      for (int ks_ = 0; ks_ < 4; ++ks_) {                               \
        st0 = __builtin_amdgcn_mfma_f32_32x32x16_bf16(KF[2*ks_],   qf[2*ks_],   st0, 0, 0, 0); \
        st1 = __builtin_amdgcn_mfma_f32_32x32x16_bf16(KF[2*ks_+1], qf[2*ks_+1], st1, 0, 0, 0); \
      }                                                                 \
      const bool diag_ = ((JT) == it);                                  \
      float pw[16]; float rsl_ = 0.f;                                   \
      _Pragma("unroll")                                                 \
      for (int r_ = 0; r_ < 16; ++r_) {                                 \
        const int jl_ = (r_&3) + 8*(r_>>2) + 4*hi;                      \
        const float av_ = F4C(AF[r_>>2], r_&3);                         \
        float cv_ = (st0[r_] + st1[r_]) * __expf(av_ - Mi);             \
        if (diag_ && jl_ > q32) cv_ = 0.f;                              \
        pw[r_] = cv_; rsl_ += cv_;                                      \
      }                                                                 \
      rs += rsl_;                                                       \
      unsigned w00 = pk2(pw[0],pw[1]),   w02 = pk2(pw[4],pw[5]);        \
      unsigned w01 = pk2(pw[2],pw[3]),   w03 = pk2(pw[6],pw[7]);        \
      unsigned w10 = pk2(pw[8],pw[9]),   w12 = pk2(pw[12],pw[13]);      \
      unsigned w11 = pk2(pw[10],pw[11]), w13 = pk2(pw[14],pw[15]);      \
      lane32_swap(w00, w02); lane32_swap(w01, w03);                     \
      lane32_swap(w10, w12); lane32_swap(w11, w13);                     \
      u32x4 a0v; a0v[0]=w00; a0v[1]=w01; a0v[2]=w02; a0v[3]=w03;        \
      u32x4 a1v; a1v[0]=w10; a1v[1]=w11; a1v[2]=w12; a1v[3]=w13;        \
      const bf16x8 pa0 = __builtin_bit_cast(bf16x8, a0v);               \
      const bf16x8 pa1 = __builtin_bit_cast(bf16x8, a1v);               \
      asm volatile("s_waitcnt vmcnt(0)" ::: "memory");                  \
      const unsigned char* vr_ = vbase + (BUFI)*8192 + lane*16;         \
      _Pragma("unroll")                                                 \
      for (int db_ = 0; db_ < 4; ++db_) {                               \
        const bf16x8 v0_ = *(const bf16x8*)(vr_ + db_*1024);            \
        const bf16x8 v1_ = *(const bf16x8*)(vr_ + (4+db_)*1024);        \
        acc[db_] = __builtin_amdgcn_mfma_f32_32x32x16_bf16(pa0, v0_, acc[db_], 0, 0, 0); \
        acc[db_] = __builtin_amdgcn_mfma_f32_32x32x16_bf16(pa1, v1_, acc[db_], 0, 0, 0); \
      }                                                                 \
      if ((NX) <= it) STAGEV(NBUF, NX);                                 \
    } while (0)

  int jt = w;
  if (jt <= it) { LOADKA(kA, aA, jt); STAGEV(0, jt); }
  while (jt <= it) {
    int nx = jt + 4;
    if (nx <= it) LOADKA(kB, aB, nx);
    BODY(kA, aA, 0, jt, nx, 1);
    jt = nx;
    if (jt > it) break;
    nx = jt + 4;
    if (nx <= it) LOADKA(kA, aA, nx);
    BODY(kB, aB, 1, jt, nx, 0);
    jt = nx;
  }
  #undef LOADKA
  #undef STAGEV
  #undef BODY

  rs += __shfl_xor(rs, 32);

  // all waves done with their V-LDS before red (union) is written
  __syncthreads();

  // ---- 2-step cross-wave tree reduction in LDS ----
  if (w >= 2) {
    #pragma unroll
    for (int db = 0; db < 4; ++db)
      #pragma unroll
      for (int r = 0; r < 16; ++r) {
        const int row = (r&3) + 8*(r>>2) + 4*hi;
        red[w-2][row][db*32 + q32] = acc[db][r];
      }
    if (lane < 32) rs_red[w-2][q32] = rs;
  }
  __syncthreads();
  if (w < 2) {
    #pragma unroll
    for (int db = 0; db < 4; ++db)
      #pragma unroll
      for (int r = 0; r < 16; ++r) {
        const int row = (r&3) + 8*(r>>2) + 4*hi;
        acc[db][r] += red[w][row][db*32 + q32];
      }
    rs += rs_red[w][q32];
    #pragma unroll
    for (int db = 0; db < 4; ++db)
      #pragma unroll
      for (int r = 0; r < 16; ++r) {
        const int row = (r&3) + 8*(r>>2) + 4*hi;
        red[w][row][db*32 + q32] = acc[db][r];
      }
    if (lane < 32) rs_red[w][q32] = rs;
  }
  __syncthreads();

  // ---- epilogue: normalizer + per-head LayerNorm ----
  {
    const int r2 = t >> 3;
    const int l8 = t & 7;
    const int i  = i0 + r2;
    const float rst = rs_red[0][r2] + rs_red[1][r2];
    const float csi = cs[h*S_LEN + i];
    const float Mi2 = M[h*S_LEN + i];
    const float norm = fmaxf(fabsf(rst), __expf(-(csi + Mi2))) + 1e-6f;
    const float inv = 1.0f / norm;
    float hv[16]; float s1 = 0.f, s2 = 0.f;
    #pragma unroll
    for (int u = 0; u < 4; ++u) {
      const int d = l8*4 + u*32;
      #pragma unroll
      for (int c2 = 0; c2 < 4; ++c2) {
        float x = (red[0][r2][d+c2] + red[1][r2][d+c2]) * inv;
        hv[u*4+c2] = x; s1 += x; s2 += x*x;
      }
    }
    s1 += __shfl_xor(s1,1); s1 += __shfl_xor(s1,2); s1 += __shfl_xor(s1,4);
    s2 += __shfl_xor(s2,1); s2 += __shfl_xor(s2,2); s2 += __shfl_xor(s2,4);
    const float mean = s1*(1.f/DHEAD);
    const float var  = s2*(1.f/DHEAD) - mean*mean;
    const float rstd = rsqrtf(var + 1e-5f);
    float* op = out + (size_t)i*EDIM + h*DHEAD;
    const float* ow = out_w + h*DHEAD;
    #pragma unroll
    for (int u = 0; u < 4; ++u) {
      const int d = l8*4 + u*32;
      float4 o;
      o.x = (hv[u*4+0]-mean)*rstd*ow[d+0];
      o.y = (hv[u*4+1]-mean)*rstd*ow[d+1];
      o.z = (hv[u*4+2]-mean)*rstd*ow[d+2];
      o.w = (hv[u*4+3]-mean)*rstd*ow[d+3];
      *((float4*)(op + d)) = o;
    }
  }
}

extern "C" void kernel_launch(void* const* d_in, const int* in_sizes, int n_in,
                              void* d_out, int out_size, void* d_ws, size_t ws_size,
                              hipStream_t stream) {
  const float* q  = (const float*)d_in[0];
  const float* k  = (const float*)d_in[1];
  const float* v  = (const float*)d_in[2];
  const float* iw = (const float*)d_in[3];
  const float* ib = (const float*)d_in[4];
  const float* fw = (const float*)d_in[5];
  const float* fb = (const float*)d_in[6];
  const float* ow = (const float*)d_in[7];
  float* out = (float*)d_out;
  float* ws = (float*)d_ws;
  float* ig = ws;
  float* fg = ws + 1*NHEAD*S_LEN;
  float* cs = ws + 2*NHEAD*S_LEN;
  float* aa = ws + 3*NHEAD*S_LEN;
  float* Mm = ws + 4*NHEAD*S_LEN;
  unsigned short* Qp = (unsigned short*)(ws + 5*NHEAD*S_LEN);
  unsigned short* Kp = Qp + (size_t)S_LEN*EDIM;
  unsigned short* Vp = Kp + (size_t)S_LEN*EDIM;

  hipLaunchKernelGGL(gates_pack_kernel, dim3(S_LEN/8), dim3(256), 0, stream,
                     q, k, v, iw, ib, fw, fb, ig, fg, Qp, Kp, Vp);
  hipLaunchKernelGGL(scan_kernel, dim3(NHEAD), dim3(256), 0, stream,
                     ig, fg, cs, aa, Mm);
  hipLaunchKernelGGL(mlstm_main, dim3(NHEAD*NT), dim3(256), 0, stream,
                     Qp, Kp, Vp, cs, aa, Mm, ow, out);
}